// Round 1
// baseline (146.170 us; speedup 1.0000x reference)
//
#include <hip/hip_runtime.h>
#include <stdint.h>

#define BS 256
#define SCAN_T 1024

// ---- helpers ----
__device__ __forceinline__ unsigned f2key(float f) {
    unsigned u = __float_as_uint(f);
    return (u & 0x80000000u) ? ~u : (u | 0x80000000u);
}
__device__ __forceinline__ float key2f(unsigned k) {
    unsigned u = (k & 0x80000000u) ? (k & 0x7FFFFFFFu) : ~k;
    return __uint_as_float(u);
}
__device__ __forceinline__ float s_val(const float* score, const int* track, int i) {
    return track[i] ? 0.0f : score[i];
}
// searchsorted(row_splits, i, 'right') - 1 over B+1 entries
__device__ __forceinline__ int find_seg(const int* rs, int B, int i) {
    int l = 0, h = B + 1;
    while (l < h) { int m = (l + h) >> 1; if (rs[m] <= i) l = m + 1; else h = m; }
    return l - 1;
}

// key(+inf) = 0xFF800000
#define KEY_INF 0xFF800000u

__global__ void k_init(unsigned* seg_min, int B) {
    int t = blockIdx.x * blockDim.x + threadIdx.x;
    if (t < B) seg_min[t] = KEY_INF;
}

__global__ void k_segmin(const float* __restrict__ score, const int* __restrict__ track,
                         const int* __restrict__ rs, int N, int B,
                         unsigned* __restrict__ seg_min) {
    __shared__ unsigned smin[1024];
    int i = blockIdx.x * blockDim.x + threadIdx.x;
    if (B <= 1024) {
        for (int t = threadIdx.x; t < B; t += blockDim.x) smin[t] = KEY_INF;
        __syncthreads();
        if (i < N) {
            float s = s_val(score, track, i);
            int seg = find_seg(rs, B, i);
            atomicMin(&smin[seg], f2key(s));
        }
        __syncthreads();
        for (int t = threadIdx.x; t < B; t += blockDim.x)
            if (smin[t] != KEY_INF) atomicMin(&seg_min[t], smin[t]);
    } else {
        if (i < N) {
            float s = s_val(score, track, i);
            int seg = find_seg(rs, B, i);
            atomicMin(&seg_min[seg], f2key(s));
        }
    }
}

__global__ void k_threshold(const unsigned* __restrict__ seg_min, int B, float* thr) {
    __shared__ float sh[BS];
    float m = -INFINITY;
    for (int t = threadIdx.x; t < B; t += blockDim.x) m = fmaxf(m, key2f(seg_min[t]));
    sh[threadIdx.x] = m;
    __syncthreads();
    for (int d = BS / 2; d > 0; d >>= 1) {
        if ((int)threadIdx.x < d) sh[threadIdx.x] = fmaxf(sh[threadIdx.x], sh[threadIdx.x + d]);
        __syncthreads();
    }
    if (threadIdx.x == 0) {
        float hm = sh[0];
        const float invR = 1.0f / 10.0f;
        *thr = (hm < invR) ? invR : (hm + 1e-7f);
    }
}

__global__ void k_count(const float* __restrict__ score, const int* __restrict__ track,
                        const float* __restrict__ thr, int N, int* __restrict__ blk_cnt) {
    int i = blockIdx.x * blockDim.x + threadIdx.x;
    float T = *thr;
    bool pred = (i < N) ? (s_val(score, track, i) <= T) : false;
    unsigned long long b = __ballot(pred);
    __shared__ int wc[BS / 64];
    int w = threadIdx.x >> 6;
    if ((threadIdx.x & 63) == 0) wc[w] = __popcll(b);
    __syncthreads();
    if (threadIdx.x == 0) {
        int s = 0;
        for (int j = 0; j < BS / 64; ++j) s += wc[j];
        blk_cnt[blockIdx.x] = s;
    }
}

// single block: exclusive scan of blk[] in place; writes total + scalar outputs
__global__ void k_scan(int* __restrict__ blk, int nb, int* __restrict__ total,
                       float* __restrict__ out_old, float* __restrict__ out_nsel, int N) {
    __shared__ int sh[SCAN_T];
    int t = threadIdx.x;
    int ept = (nb + SCAN_T - 1) / SCAN_T;
    long base = (long)t * ept;
    int mySum = 0;
    for (int j = 0; j < ept; ++j) {
        long idx = base + j;
        if (idx < nb) mySum += blk[idx];
    }
    sh[t] = mySum;
    __syncthreads();
    for (int d = 1; d < SCAN_T; d <<= 1) {
        int add = (t >= d) ? sh[t - d] : 0;
        __syncthreads();
        sh[t] += add;
        __syncthreads();
    }
    int run = sh[t] - mySum;  // exclusive base for this thread
    for (int j = 0; j < ept; ++j) {
        long idx = base + j;
        if (idx < nb) { int c = blk[idx]; blk[idx] = run; run += c; }
    }
    if (t == SCAN_T - 1) {
        int tot = sh[SCAN_T - 1];
        *total = tot;
        *out_nsel = (float)tot;
        *out_old = (float)N;
    }
}

// one wave per b in [0, B]: new_rs[b] = #selected with i < row_splits[b]
__global__ void k_newrs(const float* __restrict__ score, const int* __restrict__ track,
                        const float* __restrict__ thr, const int* __restrict__ rs,
                        const int* __restrict__ blk_off, const int* __restrict__ total,
                        int nb, float* __restrict__ out_newrs) {
    int b = blockIdx.x;
    int pos = rs[b];
    int blkI = pos / BS;
    int start = blkI * BS;
    float T = *thr;
    int cnt = 0;
    for (int i = start + (int)threadIdx.x; i < pos; i += 64) {
        if (s_val(score, track, i) <= T) cnt++;
    }
    for (int d = 32; d > 0; d >>= 1) cnt += __shfl_down(cnt, d);
    if (threadIdx.x == 0) {
        int off = (blkI < nb) ? blk_off[blkI] : *total;
        out_newrs[b] = (float)(off + cnt);
    }
}

__global__ void k_scatter(const float* __restrict__ score, const int* __restrict__ track,
                          const float* __restrict__ thr, const int* __restrict__ blk_off,
                          const int* __restrict__ total, int N, float* __restrict__ out_idx) {
    int i = blockIdx.x * blockDim.x + threadIdx.x;
    float T = *thr;
    bool pred = (i < N) ? (s_val(score, track, i) <= T) : false;
    unsigned long long b = __ballot(pred);
    int lane = threadIdx.x & 63;
    int w = threadIdx.x >> 6;
    __shared__ int wc[BS / 64];
    if (lane == 0) wc[w] = __popcll(b);
    __syncthreads();
    int waveBase = 0;
    for (int j = 0; j < w; ++j) waveBase += wc[j];
    if (pred) {
        int rank = __popcll(b & ((1ULL << (unsigned)lane) - 1ULL));
        int pos = blk_off[blockIdx.x] + waveBase + rank;
        out_idx[pos] = (float)i;
    }
    if (i < N && i >= *total) out_idx[i] = -1.0f;
}

// vectorized gather: one float4 per thread
__global__ void k_gather4(const float4* __restrict__ x4, const float* __restrict__ idxf,
                          int N, int Fv, float4* __restrict__ out4) {
    long t = (long)blockIdx.x * blockDim.x + threadIdx.x;
    long tot = (long)N * Fv;
    if (t >= tot) return;
    int p = (int)(t / Fv);
    int c = (int)(t - (long)p * Fv);
    float f = idxf[p];
    float4 v = make_float4(0.0f, 0.0f, 0.0f, 0.0f);
    if (f >= 0.0f) {
        int idx = (int)f;
        v = x4[(long)idx * Fv + c];
    }
    out4[t] = v;
}

// scalar fallback (F % 4 != 0)
__global__ void k_gather1(const float* __restrict__ x, const float* __restrict__ idxf,
                          int N, int F, float* __restrict__ out) {
    long t = (long)blockIdx.x * blockDim.x + threadIdx.x;
    long tot = (long)N * F;
    if (t >= tot) return;
    int p = (int)(t / F);
    int c = (int)(t - (long)p * F);
    float f = idxf[p];
    float v = 0.0f;
    if (f >= 0.0f) {
        int idx = (int)f;
        v = x[(long)idx * F + c];
    }
    out[t] = v;
}

extern "C" void kernel_launch(void* const* d_in, const int* in_sizes, int n_in,
                              void* d_out, int out_size, void* d_ws, size_t ws_size,
                              hipStream_t stream) {
    const float* x     = (const float*)d_in[0];
    const float* score = (const float*)d_in[1];
    const int*   track = (const int*)d_in[2];
    const int*   rs    = (const int*)d_in[3];

    int N = in_sizes[1];            // score flat count
    int F = in_sizes[0] / N;        // 32
    int B = in_sizes[3] - 1;        // 64
    int nb = (N + BS - 1) / BS;

    // workspace layout
    unsigned* seg_min = (unsigned*)d_ws;        // B
    float*    thr     = (float*)(seg_min + B);  // 1
    int*      total   = (int*)(thr + 1);        // 1
    int*      blk     = (int*)(total + 1);      // nb (counts -> exclusive offsets)

    // output layout (all stored as float32 values)
    float* out      = (float*)d_out;
    long off_rs   = (long)N * F;
    long off_old  = off_rs + (B + 1);
    long off_idx  = off_old + 1;
    long off_nsel = off_idx + N;

    float* out_rs   = out + off_rs;
    float* out_old  = out + off_old;
    float* out_idx  = out + off_idx;
    float* out_nsel = out + off_nsel;

    k_init<<<(B + BS - 1) / BS, BS, 0, stream>>>(seg_min, B);
    k_segmin<<<nb, BS, 0, stream>>>(score, track, rs, N, B, seg_min);
    k_threshold<<<1, BS, 0, stream>>>(seg_min, B, thr);
    k_count<<<nb, BS, 0, stream>>>(score, track, thr, N, blk);
    k_scan<<<1, SCAN_T, 0, stream>>>(blk, nb, total, out_old, out_nsel, N);
    k_newrs<<<B + 1, 64, 0, stream>>>(score, track, thr, rs, blk, total, nb, out_rs);
    k_scatter<<<nb, BS, 0, stream>>>(score, track, thr, blk, total, N, out_idx);

    if ((F & 3) == 0) {
        int Fv = F >> 2;
        long tot = (long)N * Fv;
        int blocks = (int)((tot + BS - 1) / BS);
        k_gather4<<<blocks, BS, 0, stream>>>((const float4*)x, out_idx, N, Fv, (float4*)d_out);
    } else {
        long tot = (long)N * F;
        int blocks = (int)((tot + BS - 1) / BS);
        k_gather1<<<blocks, BS, 0, stream>>>(x, out_idx, N, F, (float*)d_out);
    }
}